// Round 1
// baseline (509.396 us; speedup 1.0000x reference)
//
#include <hip/hip_runtime.h>

#define NN 512
#define CC 1024
#define OO 256
#define VV 68
#define PP 7
#define NC (NN*CC)
#define NV_CNT 34816.0f   // N*T*V = 512*68

__device__ __forceinline__ int part_of(int v){
  return (v>=17)+(v>=22)+(v>=27)+(v>=36)+(v>=42)+(v>=48);
}

// K1: per (n,c) row: part sums and sums-of-squares over V=68.
// S/S2 layout: [p][n*C + c]  (coalesced writes here, coalesced reads in K3,
// wave-uniform reads in K2).
__global__ __launch_bounds__(256) void k1_partsum(const float* __restrict__ x,
    float* __restrict__ S, float* __restrict__ S2){
  int r = blockIdx.x*256 + threadIdx.x;          // row = n*C + c, 272B-aligned
  const float4* xr = (const float4*)(x + (size_t)r*VV);
  float s[PP], q[PP];
  #pragma unroll
  for (int p=0;p<PP;p++){ s[p]=0.f; q[p]=0.f; }
  #pragma unroll
  for (int i=0;i<17;i++){
    float4 v4 = xr[i];
    #pragma unroll
    for (int j=0;j<4;j++){
      int v = i*4+j;
      int p = part_of(v);                        // folds to constant
      float e = (j==0)?v4.x:(j==1)?v4.y:(j==2)?v4.z:v4.w;
      s[p] += e;
      q[p] = fmaf(e, e, q[p]);
    }
  }
  #pragma unroll
  for (int p=0;p<PP;p++){
    S [p*NC + r] = s[p];
    S2[p*NC + r] = q[p];
  }
}

// K2: per 2 n's: h[o,p] = (1/cnt_p)*sum_c S[n,c,p]*w1[o,c] + b1[o];
// att[n,p] = softmax_p(w2_0*mean_o h + w2_1*max_o h + b2).
// S addresses are wave-uniform -> scalar loads; w1 per-thread float4 rows.
__global__ __launch_bounds__(256) void k2_att(const float* __restrict__ S,
    const float* __restrict__ w1, const float* __restrict__ b1,
    const float* __restrict__ w2, const float* __restrict__ b2,
    float* __restrict__ att){
  int n0 = blockIdx.x*2;
  int o = threadIdx.x;
  float acc[2][PP];
  #pragma unroll
  for (int n2=0;n2<2;n2++)
    #pragma unroll
    for (int p=0;p<PP;p++) acc[n2][p] = 0.f;

  const float4* w4p = (const float4*)(w1 + o*CC);
  const float* Sb = S + n0*CC;                   // + p*NC + n2*CC + c
  for (int cb=0;cb<CC/4;cb++){
    float4 w4 = w4p[cb];
    #pragma unroll
    for (int j=0;j<4;j++){
      int c = cb*4+j;
      float wv = (j==0)?w4.x:(j==1)?w4.y:(j==2)?w4.z:w4.w;
      #pragma unroll
      for (int p=0;p<PP;p++){
        acc[0][p] = fmaf(wv, Sb[p*NC + c],      acc[0][p]);
        acc[1][p] = fmaf(wv, Sb[p*NC + CC + c], acc[1][p]);
      }
    }
  }

  const float inv_cnt[PP] = {1.f/17.f,1.f/5.f,1.f/5.f,1.f/9.f,1.f/6.f,1.f/6.f,1.f/20.f};
  float bo = b1[o];
  __shared__ float red_s[4][2][PP];
  __shared__ float red_m[4][2][PP];
  __shared__ float pre_s[2][PP];
  int lane = threadIdx.x & 63, wid = threadIdx.x >> 6;
  #pragma unroll
  for (int n2=0;n2<2;n2++){
    #pragma unroll
    for (int p=0;p<PP;p++){
      float h = fmaf(acc[n2][p], inv_cnt[p], bo);
      float sm = h, mx = h;
      #pragma unroll
      for (int off=32; off>0; off>>=1){
        sm += __shfl_down(sm, off, 64);
        mx = fmaxf(mx, __shfl_down(mx, off, 64));
      }
      if (lane==0){ red_s[wid][n2][p]=sm; red_m[wid][n2][p]=mx; }
    }
  }
  __syncthreads();
  if (threadIdx.x < 2*PP){
    int n2 = threadIdx.x/PP, p = threadIdx.x%PP;
    float sm = red_s[0][n2][p]+red_s[1][n2][p]+red_s[2][n2][p]+red_s[3][n2][p];
    float mx = fmaxf(fmaxf(red_m[0][n2][p],red_m[1][n2][p]),
                     fmaxf(red_m[2][n2][p],red_m[3][n2][p]));
    pre_s[n2][p] = w2[0]*(sm*(1.f/(float)OO)) + w2[1]*mx + b2[0];
  }
  __syncthreads();
  if (threadIdx.x < 2){
    int n2 = threadIdx.x;
    float m = pre_s[n2][0];
    #pragma unroll
    for (int p=1;p<PP;p++) m = fmaxf(m, pre_s[n2][p]);
    float e[PP], sum=0.f;
    #pragma unroll
    for (int p=0;p<PP;p++){ e[p] = expf(pre_s[n2][p]-m); sum += e[p]; }
    float inv = 1.f/sum;
    #pragma unroll
    for (int p=0;p<PP;p++) att[(n0+n2)*PP+p] = e[p]*inv;
  }
}

// K3: partial BN sums per channel: partial[nch][0][c] = sum_{n in chunk} sum_p att*S
//     partial[nch][1][c] = sum att^2 * S2.  256 blocks = 4 c-blocks x 64 n-chunks.
__global__ __launch_bounds__(256) void k3_stats(const float* __restrict__ S,
    const float* __restrict__ S2, const float* __restrict__ att,
    float* __restrict__ partial){
  int cb  = blockIdx.x & 3;
  int nch = blockIdx.x >> 2;                     // 0..63, 8 n each
  int c = cb*256 + threadIdx.x;
  float sm=0.f, sq=0.f;
  for (int i=0;i<8;i++){
    int n = nch*8 + i;
    #pragma unroll
    for (int p=0;p<PP;p++){
      float a = att[n*PP+p];                     // wave-uniform -> s_load
      sm = fmaf(a,   S [p*NC + n*CC + c], sm);
      sq = fmaf(a*a, S2[p*NC + n*CC + c], sq);
    }
  }
  partial[nch*2*CC + c]      = sm;
  partial[nch*2*CC + CC + c] = sq;
}

// K3b: finalize mean/var -> scale/shift per channel.
__global__ __launch_bounds__(256) void k3b_finalize(const float* __restrict__ partial,
    const float* __restrict__ gamma, const float* __restrict__ beta,
    float* __restrict__ scsh){
  int c = blockIdx.x*256 + threadIdx.x;
  float sm=0.f, sq=0.f;
  for (int ch=0;ch<64;ch++){
    sm += partial[ch*2*CC + c];
    sq += partial[ch*2*CC + CC + c];
  }
  float mean = sm * (1.0f/NV_CNT);
  float msq  = sq * (1.0f/NV_CNT);
  float var  = msq - mean*mean;
  float rstd = rsqrtf(var + 1e-5f);
  float sc = gamma[c]*rstd;
  scsh[c]      = sc;
  scsh[CC + c] = beta[c] - mean*sc;
}

// K4: out = relu( x*(att_j*scale + 1) + shift ), float4 over flat index.
// 68 % 4 == 0 so a float4 never crosses a row.
__global__ __launch_bounds__(256) void k4_out(const float* __restrict__ x,
    const float* __restrict__ att, const float* __restrict__ scsh,
    float* __restrict__ out){
  int f = blockIdx.x*256 + threadIdx.x;          // float4 index, < NC*17
  int r = f/17;
  int q = f - r*17;
  int v0 = q*4;
  int c = r & (CC-1);
  int n = r >> 10;
  float4 xv = ((const float4*)x)[f];
  float sc = scsh[c];
  float sh = scsh[CC + c];
  const float* an = att + n*PP;
  float vals[4];
  #pragma unroll
  for (int j=0;j<4;j++){
    int p = part_of(v0 + j);
    float a = an[p];
    float e = (j==0)?xv.x:(j==1)?xv.y:(j==2)?xv.z:xv.w;
    vals[j] = fmaxf(fmaf(e, fmaf(a, sc, 1.0f), sh), 0.0f);
  }
  float4 ov; ov.x=vals[0]; ov.y=vals[1]; ov.z=vals[2]; ov.w=vals[3];
  ((float4*)out)[f] = ov;
}

extern "C" void kernel_launch(void* const* d_in, const int* in_sizes, int n_in,
                              void* d_out, int out_size, void* d_ws, size_t ws_size,
                              hipStream_t stream) {
  const float* x     = (const float*)d_in[0];
  const float* w1    = (const float*)d_in[1];
  const float* b1    = (const float*)d_in[2];
  const float* w2    = (const float*)d_in[3];
  const float* b2    = (const float*)d_in[4];
  const float* gamma = (const float*)d_in[5];
  const float* beta  = (const float*)d_in[6];
  float* out = (float*)d_out;

  float* S       = (float*)d_ws;                 // 7*NC
  float* S2      = S  + 7*NC;                    // 7*NC
  float* att     = S2 + 7*NC;                    // 512*7
  float* partial = att + NN*PP;                  // 64*2*1024
  float* scsh    = partial + 64*2*CC;            // 2*1024
  // total ~29.9 MB of ws

  k1_partsum  <<<NC/256,      256, 0, stream>>>(x, S, S2);
  k2_att      <<<NN/2,        256, 0, stream>>>(S, w1, b1, w2, b2, att);
  k3_stats    <<<256,         256, 0, stream>>>(S, S2, att, partial);
  k3b_finalize<<<CC/256,      256, 0, stream>>>(partial, gamma, beta, scsh);
  k4_out      <<<(NC*17)/256, 256, 0, stream>>>(x, att, scsh, out);
}

// Round 2
// 472.102 us; speedup vs baseline: 1.0790x; 1.0790x over previous
//
#include <hip/hip_runtime.h>

#define NN 512
#define CC 1024
#define OO 256
#define VV 68
#define PP 7
#define NC (NN*CC)
#define NV_CNT 34816.0f   // N*T*V = 512*68

__device__ __forceinline__ int part_of(int v){
  return (v>=17)+(v>=22)+(v>=27)+(v>=36)+(v>=42)+(v>=48);
}

// K0: repack w1 [o][c] -> w1p[cb][o] as float4 (c-block of 4 per entry).
// Makes k2's w1 reads 16B/lane coalesced (lanes = consecutive o).
__global__ __launch_bounds__(256) void k0_repack(const float* __restrict__ w1,
    float* __restrict__ w1p){
  int t = blockIdx.x*256 + threadIdx.x;          // t = cb*256 + o
  int o = t & 255, cb = t >> 8;
  float4 v = *(const float4*)(w1 + o*CC + cb*4);
  ((float4*)w1p)[t] = v;                         // coalesced write
}

// K1: per (n,c) row: part sums and sums-of-squares over V=68.
// S/S2 layout: [p][n*C + c]
__global__ __launch_bounds__(256) void k1_partsum(const float* __restrict__ x,
    float* __restrict__ S, float* __restrict__ S2){
  int r = blockIdx.x*256 + threadIdx.x;          // row = n*C + c
  const float4* xr = (const float4*)(x + (size_t)r*VV);
  float s[PP], q[PP];
  #pragma unroll
  for (int p=0;p<PP;p++){ s[p]=0.f; q[p]=0.f; }
  #pragma unroll
  for (int i=0;i<17;i++){
    float4 v4 = xr[i];
    #pragma unroll
    for (int j=0;j<4;j++){
      int v = i*4+j;
      int p = part_of(v);                        // folds to constant
      float e = (j==0)?v4.x:(j==1)?v4.y:(j==2)?v4.z:v4.w;
      s[p] += e;
      q[p] = fmaf(e, e, q[p]);
    }
  }
  #pragma unroll
  for (int p=0;p<PP;p++){
    S [p*NC + r] = s[p];
    S2[p*NC + r] = q[p];
  }
}

// K2 v2: per block: 2 n's, thread = o. w1p loads coalesced (16B/lane);
// S loads wave-uniform (expect s_load_dwordx4). acc[n2][p] in VGPRs.
__global__ __launch_bounds__(256) void k2_att(const float* __restrict__ S,
    const float* __restrict__ w1p, const float* __restrict__ b1,
    const float* __restrict__ w2, const float* __restrict__ b2,
    float* __restrict__ att){
  int n0 = blockIdx.x*2;
  int o = threadIdx.x;
  float acc[2][PP];
  #pragma unroll
  for (int n2=0;n2<2;n2++)
    #pragma unroll
    for (int p=0;p<PP;p++) acc[n2][p] = 0.f;

  const float4* wp = (const float4*)w1p;         // [cb*256 + o]
  const float* Sb = S + (size_t)n0*CC;           // + p*NC + n2*CC + c
  for (int cb=0; cb<CC/4; cb++){
    float4 w4 = wp[cb*256 + o];
    #pragma unroll
    for (int p=0;p<PP;p++){
      float4 s0 = *(const float4*)(Sb + (size_t)p*NC + cb*4);        // uniform
      float4 s1 = *(const float4*)(Sb + (size_t)p*NC + CC + cb*4);   // uniform
      acc[0][p] = fmaf(w4.x, s0.x, acc[0][p]);
      acc[0][p] = fmaf(w4.y, s0.y, acc[0][p]);
      acc[0][p] = fmaf(w4.z, s0.z, acc[0][p]);
      acc[0][p] = fmaf(w4.w, s0.w, acc[0][p]);
      acc[1][p] = fmaf(w4.x, s1.x, acc[1][p]);
      acc[1][p] = fmaf(w4.y, s1.y, acc[1][p]);
      acc[1][p] = fmaf(w4.z, s1.z, acc[1][p]);
      acc[1][p] = fmaf(w4.w, s1.w, acc[1][p]);
    }
  }

  const float inv_cnt[PP] = {1.f/17.f,1.f/5.f,1.f/5.f,1.f/9.f,1.f/6.f,1.f/6.f,1.f/20.f};
  float bo = b1[o];
  __shared__ float red_s[4][2][PP];
  __shared__ float red_m[4][2][PP];
  __shared__ float pre_s[2][PP];
  int lane = threadIdx.x & 63, wid = threadIdx.x >> 6;
  #pragma unroll
  for (int n2=0;n2<2;n2++){
    #pragma unroll
    for (int p=0;p<PP;p++){
      float h = fmaf(acc[n2][p], inv_cnt[p], bo);
      float sm = h, mx = h;
      #pragma unroll
      for (int off=32; off>0; off>>=1){
        sm += __shfl_down(sm, off, 64);
        mx = fmaxf(mx, __shfl_down(mx, off, 64));
      }
      if (lane==0){ red_s[wid][n2][p]=sm; red_m[wid][n2][p]=mx; }
    }
  }
  __syncthreads();
  if (threadIdx.x < 2*PP){
    int n2 = threadIdx.x/PP, p = threadIdx.x%PP;
    float sm = red_s[0][n2][p]+red_s[1][n2][p]+red_s[2][n2][p]+red_s[3][n2][p];
    float mx = fmaxf(fmaxf(red_m[0][n2][p],red_m[1][n2][p]),
                     fmaxf(red_m[2][n2][p],red_m[3][n2][p]));
    pre_s[n2][p] = w2[0]*(sm*(1.f/(float)OO)) + w2[1]*mx + b2[0];
  }
  __syncthreads();
  if (threadIdx.x < 2){
    int n2 = threadIdx.x;
    float m = pre_s[n2][0];
    #pragma unroll
    for (int p=1;p<PP;p++) m = fmaxf(m, pre_s[n2][p]);
    float e[PP], sum=0.f;
    #pragma unroll
    for (int p=0;p<PP;p++){ e[p] = expf(pre_s[n2][p]-m); sum += e[p]; }
    float inv = 1.f/sum;
    #pragma unroll
    for (int p=0;p<PP;p++) att[(n0+n2)*PP+p] = e[p]*inv;
  }
}

// K3: partial BN sums per channel from S/S2 and att.
__global__ __launch_bounds__(256) void k3_stats(const float* __restrict__ S,
    const float* __restrict__ S2, const float* __restrict__ att,
    float* __restrict__ partial){
  int cb  = blockIdx.x & 3;
  int nch = blockIdx.x >> 2;                     // 0..63, 8 n each
  int c = cb*256 + threadIdx.x;
  float sm=0.f, sq=0.f;
  for (int i=0;i<8;i++){
    int n = nch*8 + i;
    #pragma unroll
    for (int p=0;p<PP;p++){
      float a = att[n*PP+p];                     // wave-uniform
      sm = fmaf(a,   S [p*NC + n*CC + c], sm);
      sq = fmaf(a*a, S2[p*NC + n*CC + c], sq);
    }
  }
  partial[nch*2*CC + c]      = sm;
  partial[nch*2*CC + CC + c] = sq;
}

// K3b: finalize mean/var -> scale/shift per channel.
__global__ __launch_bounds__(256) void k3b_finalize(const float* __restrict__ partial,
    const float* __restrict__ gamma, const float* __restrict__ beta,
    float* __restrict__ scsh){
  int c = blockIdx.x*256 + threadIdx.x;
  float sm=0.f, sq=0.f;
  for (int ch=0;ch<64;ch++){
    sm += partial[ch*2*CC + c];
    sq += partial[ch*2*CC + CC + c];
  }
  float mean = sm * (1.0f/NV_CNT);
  float msq  = sq * (1.0f/NV_CNT);
  float var  = msq - mean*mean;
  float rstd = rsqrtf(var + 1e-5f);
  float sc = gamma[c]*rstd;
  scsh[c]      = sc;
  scsh[CC + c] = beta[c] - mean*sc;
}

// K4: out = relu( x*(att_j*scale + 1) + shift ), float4 over flat index.
// 17408 f4/n and 256 f4/block -> n is uniform per block (68 blocks per n).
__global__ __launch_bounds__(256) void k4_out(const float* __restrict__ x,
    const float* __restrict__ att, const float* __restrict__ scsh,
    float* __restrict__ out){
  int f = blockIdx.x*256 + threadIdx.x;          // float4 index, < NC*17
  int n = blockIdx.x / 68;                       // uniform within block
  __shared__ float s_att[PP];
  if (threadIdx.x < PP) s_att[threadIdx.x] = att[n*PP + threadIdx.x];
  __syncthreads();
  int r = f/17;
  int q = f - r*17;
  int v0 = q*4;
  int c = r & (CC-1);
  float4 xv = ((const float4*)x)[f];
  float sc = scsh[c];
  float sh = scsh[CC + c];
  float vals[4];
  #pragma unroll
  for (int j=0;j<4;j++){
    int p = part_of(v0 + j);
    float a = s_att[p];
    float e = (j==0)?xv.x:(j==1)?xv.y:(j==2)?xv.z:xv.w;
    vals[j] = fmaxf(fmaf(e, fmaf(a, sc, 1.0f), sh), 0.0f);
  }
  float4 ov; ov.x=vals[0]; ov.y=vals[1]; ov.z=vals[2]; ov.w=vals[3];
  ((float4*)out)[f] = ov;
}

extern "C" void kernel_launch(void* const* d_in, const int* in_sizes, int n_in,
                              void* d_out, int out_size, void* d_ws, size_t ws_size,
                              hipStream_t stream) {
  const float* x     = (const float*)d_in[0];
  const float* w1    = (const float*)d_in[1];
  const float* b1    = (const float*)d_in[2];
  const float* w2    = (const float*)d_in[3];
  const float* b2    = (const float*)d_in[4];
  const float* gamma = (const float*)d_in[5];
  const float* beta  = (const float*)d_in[6];
  float* out = (float*)d_out;

  float* S       = (float*)d_ws;                 // 7*NC
  float* S2      = S  + 7*NC;                    // 7*NC
  float* att     = S2 + 7*NC;                    // 512*7
  float* partial = att + NN*PP;                  // 64*2*1024
  float* scsh    = partial + 64*2*CC;            // 2*1024
  float* w1p     = scsh + 2*CC;                  // 256*1024 (1 MB)
  // total ~31 MB of ws

  k0_repack   <<<256,         256, 0, stream>>>(w1, w1p);
  k1_partsum  <<<NC/256,      256, 0, stream>>>(x, S, S2);
  k2_att      <<<NN/2,        256, 0, stream>>>(S, w1p, b1, w2, b2, att);
  k3_stats    <<<256,         256, 0, stream>>>(S, S2, att, partial);
  k3b_finalize<<<CC/256,      256, 0, stream>>>(partial, gamma, beta, scsh);
  k4_out      <<<(NC*17)/256, 256, 0, stream>>>(x, att, scsh, out);
}

// Round 3
// 331.409 us; speedup vs baseline: 1.5371x; 1.4245x over previous
//
#include <hip/hip_runtime.h>

#define NN 512
#define CC 1024
#define OO 256
#define VV 68
#define PP 7
#define NC (NN*CC)
#define NV_CNT 34816.0f   // N*T*V = 512*68

__device__ __forceinline__ int part_of(int v){
  return (v>=17)+(v>=22)+(v>=27)+(v>=36)+(v>=42)+(v>=48);
}

// K0: repack w1 [o][c] -> w1p[cb][o] as float4 (c-block of 4 per entry).
__global__ __launch_bounds__(256) void k0_repack(const float* __restrict__ w1,
    float* __restrict__ w1p){
  int t = blockIdx.x*256 + threadIdx.x;          // t = cb*256 + o
  int o = t & 255, cb = t >> 8;
  float4 v = *(const float4*)(w1 + o*CC + cb*4);
  ((float4*)w1p)[t] = v;
}

// K1 v2: LDS-transpose part-sum. 128 threads stage 128 contiguous rows
// (coalesced float4 -> each HBM line fetched once), then thread t reduces
// row t from LDS (stride 69 -> (5t+v)%32 bank pattern, 2-way = free).
__global__ __launch_bounds__(128) void k1_partsum(const float* __restrict__ x,
    float* __restrict__ S, float* __restrict__ S2){
  __shared__ float xl[128*69];                   // 35328 B
  int R = blockIdx.x*128;
  const float4* src = (const float4*)(x + (size_t)R*VV);
  #pragma unroll
  for (int it=0; it<17; it++){
    int g = it*128 + threadIdx.x;                // f4 idx in [0, 2176)
    float4 v = src[g];
    int row = g/17, qq = g - row*17;
    float* d = &xl[row*69 + qq*4];
    d[0]=v.x; d[1]=v.y; d[2]=v.z; d[3]=v.w;
  }
  __syncthreads();
  const float* r = &xl[threadIdx.x*69];
  float s[PP], q[PP];
  #pragma unroll
  for (int p=0;p<PP;p++){ s[p]=0.f; q[p]=0.f; }
  #pragma unroll
  for (int v=0; v<VV; v++){
    int p = part_of(v);                          // folds to constant
    float e = r[v];
    s[p] += e;
    q[p] = fmaf(e, e, q[p]);
  }
  int rr = R + threadIdx.x;
  #pragma unroll
  for (int p=0;p<PP;p++){
    S [p*NC + rr] = s[p];
    S2[p*NC + rr] = q[p];
  }
}

// K2a: partial GEMM  raw[n][o][p] = sum_c S[n,c,p]*w1[o,c], c split in halves
// (block) and quarters (thread). Thread t: oh=t&63 handles o=oh+64k (k<4),
// ch=t>>6 is its 128-c quarter. S half staged in LDS; reads are wave-uniform
// broadcasts. In-block reduction over ch -> hp[n][p][half][o].
__global__ __launch_bounds__(256) void k2a_gemm(const float* __restrict__ S,
    const float* __restrict__ w1p, float* __restrict__ hp){
  int n    = blockIdx.x >> 1;
  int half = blockIdx.x & 1;
  int oh = threadIdx.x & 63;
  int ch = threadIdx.x >> 6;                     // wave-uniform

  __shared__ float4 sf[896];                     // 7p x 128 f4 (14336 B)
  {
    const float* Sb = S + (size_t)n*CC + half*512;
    for (int t4 = threadIdx.x; t4 < 896; t4 += 256){
      int p = t4 >> 7, rj = t4 & 127;
      sf[t4] = *(const float4*)(Sb + (size_t)p*NC + rj*4);
    }
  }
  __syncthreads();

  float acc[4][PP];
  #pragma unroll
  for (int k=0;k<4;k++)
    #pragma unroll
    for (int p=0;p<PP;p++) acc[k][p] = 0.f;

  const float4* wp = (const float4*)w1p;
  int sbase = ch*32;
  for (int i=0;i<32;i++){
    int gcb = half*128 + ch*32 + i;
    const float4* wrow = wp + (size_t)gcb*256 + oh;
    float4 w0 = wrow[0];
    float4 w1v = wrow[64];
    float4 w2v = wrow[128];
    float4 w3v = wrow[192];
    #pragma unroll
    for (int p=0;p<PP;p++){
      float4 sv = sf[p*128 + sbase + i];         // wave-uniform broadcast
      acc[0][p] = fmaf(w0.x, sv.x, acc[0][p]);
      acc[0][p] = fmaf(w0.y, sv.y, acc[0][p]);
      acc[0][p] = fmaf(w0.z, sv.z, acc[0][p]);
      acc[0][p] = fmaf(w0.w, sv.w, acc[0][p]);
      acc[1][p] = fmaf(w1v.x, sv.x, acc[1][p]);
      acc[1][p] = fmaf(w1v.y, sv.y, acc[1][p]);
      acc[1][p] = fmaf(w1v.z, sv.z, acc[1][p]);
      acc[1][p] = fmaf(w1v.w, sv.w, acc[1][p]);
      acc[2][p] = fmaf(w2v.x, sv.x, acc[2][p]);
      acc[2][p] = fmaf(w2v.y, sv.y, acc[2][p]);
      acc[2][p] = fmaf(w2v.z, sv.z, acc[2][p]);
      acc[2][p] = fmaf(w2v.w, sv.w, acc[2][p]);
      acc[3][p] = fmaf(w3v.x, sv.x, acc[3][p]);
      acc[3][p] = fmaf(w3v.y, sv.y, acc[3][p]);
      acc[3][p] = fmaf(w3v.z, sv.z, acc[3][p]);
      acc[3][p] = fmaf(w3v.w, sv.w, acc[3][p]);
    }
  }

  // reduce the 4 c-quarters within the block, write hp[(n*7+p)*2+half][o]
  #pragma unroll
  for (int p=0;p<PP;p++){
    __syncthreads();
    sf[threadIdx.x] = make_float4(acc[0][p], acc[1][p], acc[2][p], acc[3][p]);
    __syncthreads();
    if (ch==0){
      float4 a0 = sf[oh], a1 = sf[64+oh], a2 = sf[128+oh], a3 = sf[192+oh];
      int base = ((n*PP + p)*2 + half)*256 + oh;
      hp[base      ] = a0.x+a1.x+a2.x+a3.x;
      hp[base +  64] = a0.y+a1.y+a2.y+a3.y;
      hp[base + 128] = a0.z+a1.z+a2.z+a3.z;
      hp[base + 192] = a0.w+a1.w+a2.w+a3.w;
    }
  }
}

// K2b: per n: h[o][p] = inv_cnt*sum_half hp + b1[o]; mean/max over o;
// softmax over p -> att[n][p].
__global__ __launch_bounds__(256) void k2b_soft(const float* __restrict__ hp,
    const float* __restrict__ b1, const float* __restrict__ w2,
    const float* __restrict__ b2, float* __restrict__ att){
  int n = blockIdx.x;
  int o = threadIdx.x;
  const float inv_cnt[PP] = {1.f/17.f,1.f/5.f,1.f/5.f,1.f/9.f,1.f/6.f,1.f/6.f,1.f/20.f};
  float bo = b1[o];
  float h[PP];
  #pragma unroll
  for (int p=0;p<PP;p++){
    int base = ((n*PP + p)*2)*256 + o;
    float a = hp[base] + hp[base + 256];
    h[p] = fmaf(a, inv_cnt[p], bo);
  }
  __shared__ float red_s[4][PP];
  __shared__ float red_m[4][PP];
  __shared__ float pre[PP];
  int lane = o & 63, wid = o >> 6;
  #pragma unroll
  for (int p=0;p<PP;p++){
    float sm = h[p], mx = h[p];
    #pragma unroll
    for (int off=32; off>0; off>>=1){
      sm += __shfl_down(sm, off, 64);
      mx = fmaxf(mx, __shfl_down(mx, off, 64));
    }
    if (lane==0){ red_s[wid][p]=sm; red_m[wid][p]=mx; }
  }
  __syncthreads();
  if (o < PP){
    int p = o;
    float sm = red_s[0][p]+red_s[1][p]+red_s[2][p]+red_s[3][p];
    float mx = fmaxf(fmaxf(red_m[0][p],red_m[1][p]),
                     fmaxf(red_m[2][p],red_m[3][p]));
    pre[p] = w2[0]*(sm*(1.f/(float)OO)) + w2[1]*mx + b2[0];
  }
  __syncthreads();
  if (o == 0){
    float m = pre[0];
    #pragma unroll
    for (int p=1;p<PP;p++) m = fmaxf(m, pre[p]);
    float e[PP], sum=0.f;
    #pragma unroll
    for (int p=0;p<PP;p++){ e[p] = expf(pre[p]-m); sum += e[p]; }
    float inv = 1.f/sum;
    #pragma unroll
    for (int p=0;p<PP;p++) att[n*PP+p] = e[p]*inv;
  }
}

// K3: partial BN sums per channel from S/S2 and att.
__global__ __launch_bounds__(256) void k3_stats(const float* __restrict__ S,
    const float* __restrict__ S2, const float* __restrict__ att,
    float* __restrict__ partial){
  int cb  = blockIdx.x & 3;
  int nch = blockIdx.x >> 2;                     // 0..63, 8 n each
  int c = cb*256 + threadIdx.x;
  float sm=0.f, sq=0.f;
  for (int i=0;i<8;i++){
    int n = nch*8 + i;
    #pragma unroll
    for (int p=0;p<PP;p++){
      float a = att[n*PP+p];
      sm = fmaf(a,   S [p*NC + n*CC + c], sm);
      sq = fmaf(a*a, S2[p*NC + n*CC + c], sq);
    }
  }
  partial[nch*2*CC + c]      = sm;
  partial[nch*2*CC + CC + c] = sq;
}

// K3b: finalize mean/var -> scale/shift per channel.
__global__ __launch_bounds__(256) void k3b_finalize(const float* __restrict__ partial,
    const float* __restrict__ gamma, const float* __restrict__ beta,
    float* __restrict__ scsh){
  int c = blockIdx.x*256 + threadIdx.x;
  float sm=0.f, sq=0.f;
  for (int ch=0;ch<64;ch++){
    sm += partial[ch*2*CC + c];
    sq += partial[ch*2*CC + CC + c];
  }
  float mean = sm * (1.0f/NV_CNT);
  float msq  = sq * (1.0f/NV_CNT);
  float var  = msq - mean*mean;
  float rstd = rsqrtf(var + 1e-5f);
  float sc = gamma[c]*rstd;
  scsh[c]      = sc;
  scsh[CC + c] = beta[c] - mean*sc;
}

// K4: out = relu( x*(att_j*scale + 1) + shift ), float4 over flat index.
__global__ __launch_bounds__(256) void k4_out(const float* __restrict__ x,
    const float* __restrict__ att, const float* __restrict__ scsh,
    float* __restrict__ out){
  int f = blockIdx.x*256 + threadIdx.x;          // float4 index, < NC*17
  int n = blockIdx.x / 68;                       // uniform within block
  __shared__ float s_att[PP];
  if (threadIdx.x < PP) s_att[threadIdx.x] = att[n*PP + threadIdx.x];
  __syncthreads();
  int r = f/17;
  int q = f - r*17;
  int v0 = q*4;
  int c = r & (CC-1);
  float4 xv = ((const float4*)x)[f];
  float sc = scsh[c];
  float sh = scsh[CC + c];
  float vals[4];
  #pragma unroll
  for (int j=0;j<4;j++){
    int p = part_of(v0 + j);
    float a = s_att[p];
    float e = (j==0)?xv.x:(j==1)?xv.y:(j==2)?xv.z:xv.w;
    vals[j] = fmaxf(fmaf(e, fmaf(a, sc, 1.0f), sh), 0.0f);
  }
  float4 ov; ov.x=vals[0]; ov.y=vals[1]; ov.z=vals[2]; ov.w=vals[3];
  ((float4*)out)[f] = ov;
}

extern "C" void kernel_launch(void* const* d_in, const int* in_sizes, int n_in,
                              void* d_out, int out_size, void* d_ws, size_t ws_size,
                              hipStream_t stream) {
  const float* x     = (const float*)d_in[0];
  const float* w1    = (const float*)d_in[1];
  const float* b1    = (const float*)d_in[2];
  const float* w2    = (const float*)d_in[3];
  const float* b2    = (const float*)d_in[4];
  const float* gamma = (const float*)d_in[5];
  const float* beta  = (const float*)d_in[6];
  float* out = (float*)d_out;

  float* S       = (float*)d_ws;                 // 7*NC
  float* S2      = S  + 7*NC;                    // 7*NC
  float* att     = S2 + 7*NC;                    // 512*7
  float* partial = att + NN*PP;                  // 64*2*1024
  float* scsh    = partial + 64*2*CC;            // 2*1024
  float* w1p     = scsh + 2*CC;                  // 256*1024 (1 MB)
  float* hp      = w1p + OO*CC;                  // 512*7*2*256 (7.3 MB)
  // total ~38.3 MB of ws

  k0_repack   <<<256,         256, 0, stream>>>(w1, w1p);
  k1_partsum  <<<NC/128,      128, 0, stream>>>(x, S, S2);
  k2a_gemm    <<<NN*2,        256, 0, stream>>>(S, w1p, hp);
  k2b_soft    <<<NN,          256, 0, stream>>>(hp, b1, w2, b2, att);
  k3_stats    <<<256,         256, 0, stream>>>(S, S2, att, partial);
  k3b_finalize<<<CC/256,      256, 0, stream>>>(partial, gamma, beta, scsh);
  k4_out      <<<(NC*17)/256, 256, 0, stream>>>(x, att, scsh, out);
}